// Round 13
// baseline (260.273 us; speedup 1.0000x reference)
//
#include <hip/hip_runtime.h>
#include <math.h>

#define G    4      // segments per block
#define CAP  108    // max staged rows per group (mean 80, sd ~9 -> ~0.1% fallback)

// ---------------------------------------------------------------------------
__global__ void k_segstarts(const int* __restrict__ map, int* __restrict__ starts,
                            int V, int S) {
    int i = blockIdx.x * blockDim.x + threadIdx.x;
    if (i >= V) return;
    int cur  = map[i];
    int prev = (i == 0) ? -1 : map[i - 1];
    for (int s = prev + 1; s <= cur; ++s) starts[s] = i;
    if (i == V - 1) {
        for (int s = cur + 1; s <= S; ++s) starts[s] = V;
    }
}

__device__ __forceinline__ unsigned f2bf_rte(float x) {          // RTNE -> top 16
    unsigned b = __float_as_uint(x);
    b += 0x7FFFu + ((b >> 16) & 1u);
    return b >> 16;
}
__device__ __forceinline__ float bfu_lo(unsigned u) {
    return __uint_as_float(u << 16);
}
__device__ __forceinline__ float bfu_hi(unsigned u) {
    return __uint_as_float(u & 0xFFFF0000u);
}

// M16[i][j] = bf16( sum_h Wk[h][i]*Wv[h][j] ) ;  Wt16[i][o] = bf16( Wo[o][i] )
__global__ void k_prep(const float* __restrict__ Wk, const float* __restrict__ Wv,
                       const float* __restrict__ Wo,
                       unsigned short* __restrict__ M16,
                       unsigned short* __restrict__ Wt16) {
    int i = blockIdx.x;
    int j = threadIdx.x;
    float acc = 0.f;
#pragma unroll 8
    for (int h = 0; h < 128; ++h)
        acc += Wk[h * 128 + i] * Wv[h * 128 + j];
    M16[i * 128 + j]  = (unsigned short)f2bf_rte(acc);
    Wt16[i * 128 + j] = (unsigned short)f2bf_rte(Wo[j * 128 + i]);
}

// ---------------------------------------------------------------------------
// k_main: R12 structure, 5 blocks/CU (LDS 31.75 KB, VGPR target <=102).
// Phases: stage(bf16) -> mean -> qGEMM(once/block) -> attn -> outGEMM.
// ---------------------------------------------------------------------------
__global__ __launch_bounds__(256, 5) void k_main(
    const float* __restrict__ E, const int* __restrict__ starts,
    const unsigned short* __restrict__ M16, const unsigned short* __restrict__ Wt16,
    float* __restrict__ out, int V, int S)
{
    __shared__ unsigned sA[CAP][64];   // bf16-packed rows (27.0 KB)
    __shared__ float    sE[G][128];    // ebar, later etilde (2 KB)
    __shared__ float    sQ[G][128];    // q / GEMM partial buffer (2 KB)

    const int tid  = threadIdx.x;
    const int w    = tid >> 6;       // wave id = local segment id
    const int lane = tid & 63;
    const int s0   = blockIdx.x * G;

    const int se    = min(s0 + G, S);
    const int gr0   = starts[s0];
    const int nrows = starts[se] - gr0;
    const bool staged = (nrows <= CAP);

    const int c  = lane & 31;        // column quad (sweeps)
    const int g  = lane >> 5;        // row parity (sweeps)
    const int j  = tid & 127;        // GEMM output column
    const int ih = tid >> 7;         // GEMM i-half (0/1)

    // ---------------- stage: E rows -> bf16 LDS (batches of 5/5/4) ---------
    if (staged && nrows > 0) {
        const int q4 = tid & 31;
        const int rr = tid >> 5;                 // 0..7, stride 8
        const float* gp = E + (size_t)gr0 * 128 + q4 * 4;
#pragma unroll
        for (int b = 0; b < 3; ++b) {
            const int nb = (b == 2) ? 4 : 5;
            const int k0 = b * 5;
            float4 t[5];
            for (int k = 0; k < nb; ++k) {
                const int r = min(rr + (k0 + k) * 8, nrows - 1);   // clamp: dup
                t[k] = *(const float4*)(gp + (size_t)r * 128);
            }
            for (int k = 0; k < nb; ++k) {
                const int row = rr + (k0 + k) * 8;
                if (row < CAP) {
                    uint2 u;
                    u.x = f2bf_rte(t[k].x) | (f2bf_rte(t[k].y) << 16);
                    u.y = f2bf_rte(t[k].z) | (f2bf_rte(t[k].w) << 16);
                    *(uint2*)&sA[row][q4 * 2] = u;                 // dup unread
                }
            }
        }
    }
    __syncthreads();                                            // B1

    // per-wave segment meta
    const int segi = s0 + w;
    int r0 = 0, n = 0, off = 0;
    if (segi < S) {
        r0  = starts[segi];
        n   = starts[segi + 1] - r0;
        off = r0 - gr0;
    }

    // ---------------- mean: ebar[w] ----------------------------------------
    {
        float4 sum = make_float4(0.f, 0.f, 0.f, 0.f);
        if (segi < S && n > 0) {
            if (staged) {
#pragma unroll 4
                for (int rp = 0; rp < n; rp += 2) {
                    const int row = rp + g;
                    const int rcl = min(row, n - 1);
                    const uint2 u = *(const uint2*)&sA[off + rcl][c * 2];
                    const float m = (row < n) ? 1.f : 0.f;
                    sum.x += m * bfu_lo(u.x); sum.y += m * bfu_hi(u.x);
                    sum.z += m * bfu_lo(u.y); sum.w += m * bfu_hi(u.y);
                }
            } else {
                const float* bp = E + (size_t)r0 * 128 + c * 4;
#pragma unroll 4
                for (int rp = 0; rp < n; rp += 2) {
                    const int row = rp + g;
                    const int rcl = min(row, n - 1);
                    const float4 ev = *(const float4*)(bp + (size_t)rcl * 128);
                    const float m = (row < n) ? 1.f : 0.f;
                    sum.x += m * ev.x; sum.y += m * ev.y;
                    sum.z += m * ev.z; sum.w += m * ev.w;
                }
            }
            sum.x += __shfl_xor(sum.x, 32);
            sum.y += __shfl_xor(sum.y, 32);
            sum.z += __shfl_xor(sum.z, 32);
            sum.w += __shfl_xor(sum.w, 32);
            const float inv = 1.0f / (float)n;
            sum.x *= inv; sum.y *= inv; sum.z *= inv; sum.w *= inv;
        }
        if (g == 0)
            *(float4*)&sE[w][c * 4] = sum;    // zeros when segi>=S or n==0
    }
    __syncthreads();                                            // B2

    // ---------------- q GEMM: sQ = sE @ M16 (M read once per block) --------
    {
        const unsigned short* Mb = M16 + (size_t)(ih * 64) * 128 + j;
        float a0 = 0.f, a1 = 0.f, a2 = 0.f, a3 = 0.f;
        const float* e0 = &sE[0][ih * 64];
        const float* e1 = &sE[1][ih * 64];
        const float* e2 = &sE[2][ih * 64];
        const float* e3 = &sE[3][ih * 64];
#pragma unroll 16
        for (int i = 0; i < 64; ++i) {
            const float m = __uint_as_float(((unsigned)Mb[(size_t)i * 128]) << 16);
            a0 += m * e0[i]; a1 += m * e1[i];
            a2 += m * e2[i]; a3 += m * e3[i];
        }
        if (ih == 1) {
            sQ[0][j] = a0; sQ[1][j] = a1; sQ[2][j] = a2; sQ[3][j] = a3;
        }
        __syncthreads();                                        // B3
        if (ih == 0) {
            sQ[0][j] += a0; sQ[1][j] += a1; sQ[2][j] += a2; sQ[3][j] += a3;
        }
    }
    __syncthreads();                                            // B4

    // ---------------- attn: merged scores + exp2 + weighted sum ------------
    {
        float4 acc = make_float4(0.f, 0.f, 0.f, 0.f);
        float Z = 0.f;
        if (segi < S && n > 0) {
            // pre-scale q by log2(e): exp(s) == exp2(s * log2e), exact math
            const float LOG2E = 1.4426950408889634f;
            float4 qv = *(const float4*)&sQ[w][c * 4];
            qv.x *= LOG2E; qv.y *= LOG2E; qv.z *= LOG2E; qv.w *= LOG2E;
            if (staged) {
#pragma unroll 4
                for (int rp = 0; rp < n; rp += 2) {
                    const int row = rp + g;
                    const int rcl = min(row, n - 1);
                    const uint2 u = *(const uint2*)&sA[off + rcl][c * 2];
                    const float e0 = bfu_lo(u.x), e1 = bfu_hi(u.x);
                    const float e2 = bfu_lo(u.y), e3 = bfu_hi(u.y);
                    float pd = e0 * qv.x + e1 * qv.y + e2 * qv.z + e3 * qv.w;
                    pd += __shfl_xor(pd, 1);
                    pd += __shfl_xor(pd, 2);
                    pd += __shfl_xor(pd, 4);
                    pd += __shfl_xor(pd, 8);
                    pd += __shfl_xor(pd, 16);
                    const float wgt = (row < n) ? exp2f(pd) : 0.f;
                    Z += wgt;
                    acc.x += wgt * e0; acc.y += wgt * e1;
                    acc.z += wgt * e2; acc.w += wgt * e3;
                }
            } else {
                const float* bp = E + (size_t)r0 * 128 + c * 4;
#pragma unroll 4
                for (int rp = 0; rp < n; rp += 2) {
                    const int row = rp + g;
                    const int rcl = min(row, n - 1);
                    const float4 ev = *(const float4*)(bp + (size_t)rcl * 128);
                    float pd = ev.x * qv.x + ev.y * qv.y
                             + ev.z * qv.z + ev.w * qv.w;
                    pd += __shfl_xor(pd, 1);
                    pd += __shfl_xor(pd, 2);
                    pd += __shfl_xor(pd, 4);
                    pd += __shfl_xor(pd, 8);
                    pd += __shfl_xor(pd, 16);
                    const float wgt = (row < n) ? exp2f(pd) : 0.f;
                    Z += wgt;
                    acc.x += wgt * ev.x; acc.y += wgt * ev.y;
                    acc.z += wgt * ev.z; acc.w += wgt * ev.w;
                }
            }
            acc.x += __shfl_xor(acc.x, 32);
            acc.y += __shfl_xor(acc.y, 32);
            acc.z += __shfl_xor(acc.z, 32);
            acc.w += __shfl_xor(acc.w, 32);
            Z     += __shfl_xor(Z, 32);
            const float invZ = 1.0f / Z;
            acc.x *= invZ; acc.y *= invZ; acc.z *= invZ; acc.w *= invZ;
        }
        if (g == 0)
            *(float4*)&sE[w][c * 4] = acc;    // etilde (zeros if empty)
    }
    __syncthreads();                                            // B5

    // ---------------- out GEMM: out = sE @ Wt16 (Wt read once per block) ---
    {
        const unsigned short* Wb = Wt16 + (size_t)(ih * 64) * 128 + j;
        float a0 = 0.f, a1 = 0.f, a2 = 0.f, a3 = 0.f;
        const float* e0 = &sE[0][ih * 64];
        const float* e1 = &sE[1][ih * 64];
        const float* e2 = &sE[2][ih * 64];
        const float* e3 = &sE[3][ih * 64];
#pragma unroll 16
        for (int i = 0; i < 64; ++i) {
            const float m = __uint_as_float(((unsigned)Wb[(size_t)i * 128]) << 16);
            a0 += m * e0[i]; a1 += m * e1[i];
            a2 += m * e2[i]; a3 += m * e3[i];
        }
        if (ih == 1) {
            sQ[0][j] = a0; sQ[1][j] = a1; sQ[2][j] = a2; sQ[3][j] = a3;
        }
        __syncthreads();                                        // B6
        if (ih == 0) {
            if (s0 + 0 < S) out[(size_t)(s0 + 0) * 128 + j] = sQ[0][j] + a0;
            if (s0 + 1 < S) out[(size_t)(s0 + 1) * 128 + j] = sQ[1][j] + a1;
            if (s0 + 2 < S) out[(size_t)(s0 + 2) * 128 + j] = sQ[2][j] + a2;
            if (s0 + 3 < S) out[(size_t)(s0 + 3) * 128 + j] = sQ[3][j] + a3;
        }
    }
}

// ---------------------------------------------------------------------------
extern "C" void kernel_launch(void* const* d_in, const int* in_sizes, int n_in,
                              void* d_out, int out_size, void* d_ws, size_t ws_size,
                              hipStream_t stream) {
    const float* E   = (const float*)d_in[0];
    const int*   map = (const int*)d_in[1];
    const float* Wk  = (const float*)d_in[3];
    const float* Wv  = (const float*)d_in[4];
    const float* Wo  = (const float*)d_in[5];
    float* out = (float*)d_out;

    const int V = in_sizes[1];
    const int S = out_size / 128;

    char* p = (char*)d_ws;
    auto alloc = [&](size_t b) {
        char* r = p;
        p += (b + 255) & ~(size_t)255;
        return r;
    };
    int*            starts = (int*)alloc((size_t)(S + 1) * sizeof(int));
    unsigned short* M16    = (unsigned short*)alloc(128 * 128 * sizeof(unsigned short));
    unsigned short* Wt16   = (unsigned short*)alloc(128 * 128 * sizeof(unsigned short));

    k_segstarts<<<(V + 255) / 256, 256, 0, stream>>>(map, starts, V, S);
    k_prep<<<128, 128, 0, stream>>>(Wk, Wv, Wo, M16, Wt16);
    k_main<<<(S + G - 1) / G, 256, 0, stream>>>(E, starts, M16, Wt16, out, V, S);
}

// Round 14
// 144.899 us; speedup vs baseline: 1.7962x; 1.7962x over previous
//
#include <hip/hip_runtime.h>
#include <math.h>

#define G    4      // segments per block
#define CAP  104    // max staged rows per group (~0.4% fallback)

typedef __attribute__((ext_vector_type(8))) short bf16x8;
typedef __attribute__((ext_vector_type(4))) float f32x4;

// ---------------------------------------------------------------------------
__global__ void k_segstarts(const int* __restrict__ map, int* __restrict__ starts,
                            int V, int S) {
    int i = blockIdx.x * blockDim.x + threadIdx.x;
    if (i >= V) return;
    int cur  = map[i];
    int prev = (i == 0) ? -1 : map[i - 1];
    for (int s = prev + 1; s <= cur; ++s) starts[s] = i;
    if (i == V - 1) {
        for (int s = cur + 1; s <= S; ++s) starts[s] = V;
    }
}

__device__ __forceinline__ unsigned f2bf_rte(float x) {          // RTNE -> top 16
    unsigned b = __float_as_uint(x);
    b += 0x7FFFu + ((b >> 16) & 1u);
    return b >> 16;
}
__device__ __forceinline__ float bfu_lo(unsigned u) {
    return __uint_as_float(u << 16);
}
__device__ __forceinline__ float bfu_hi(unsigned u) {
    return __uint_as_float(u & 0xFFFF0000u);
}

// ---------------------------------------------------------------------------
// k_prep: compute M = Wk^T Wv and Wt = Wo^T, then store both in MFMA
// B-fragment order (bf16), so k_main loads one uint4 per lane per fragment.
// Fragment model (16x16x32): B col = lane&15, k = (lane>>4)*8 + t.
// ushort index = ((f*64 + lane)*8 + t), f = kt*8 + jt.
// (Any k-permutation error cancels: A is packed with the same convention.)
// ---------------------------------------------------------------------------
__global__ void k_prep(const float* __restrict__ Wk, const float* __restrict__ Wv,
                       const float* __restrict__ Wo,
                       unsigned short* __restrict__ Mpk,
                       unsigned short* __restrict__ Wpk) {
    const int i = blockIdx.x;     // k dim 0..127
    const int j = threadIdx.x;    // col  0..127
    float acc = 0.f;
#pragma unroll 8
    for (int h = 0; h < 128; ++h)
        acc += Wk[h * 128 + i] * Wv[h * 128 + j];

    const int kt  = i >> 5;
    const int kg  = (i >> 3) & 3;
    const int t   = i & 7;
    const int jt  = j >> 4;
    const int l16 = j & 15;
    const int lane = kg * 16 + l16;
    const size_t idx = ((size_t)(kt * 8 + jt) * 64 + lane) * 8 + t;
    Mpk[idx] = (unsigned short)f2bf_rte(acc);
    Wpk[idx] = (unsigned short)f2bf_rte(Wo[j * 128 + i]);
}

// pack 8 consecutive fp32 -> bf16x8 (truncation)
__device__ __forceinline__ bf16x8 pack_a8(const float* p) {
    union { unsigned u[4]; bf16x8 v; } r;
    const float4 f0 = *(const float4*)p;
    const float4 f1 = *(const float4*)(p + 4);
    r.u[0] = (__float_as_uint(f0.y) & 0xFFFF0000u) | (__float_as_uint(f0.x) >> 16);
    r.u[1] = (__float_as_uint(f0.w) & 0xFFFF0000u) | (__float_as_uint(f0.z) >> 16);
    r.u[2] = (__float_as_uint(f1.y) & 0xFFFF0000u) | (__float_as_uint(f1.x) >> 16);
    r.u[3] = (__float_as_uint(f1.w) & 0xFFFF0000u) | (__float_as_uint(f1.z) >> 16);
    return r.v;
}

// ---------------------------------------------------------------------------
// k_main: R12 structure (bf16 E staged once in LDS) with MFMA GEMM phases.
// Phases: stage -> B1 -> mean -> B2 -> qGEMM(mfma) -> B3 -> attn -> B4
//         -> outGEMM(mfma) -> global.
// Wave w handles col-tiles {2w, 2w+1}; A rows 0-3 = segments (rows 4-15 dup).
// C layout (m89-verified): col=lane&15, row=(lane>>4)*4+reg -> lanes 0-15.
// ---------------------------------------------------------------------------
__global__ __launch_bounds__(256, 4) void k_main(
    const float* __restrict__ E, const int* __restrict__ starts,
    const unsigned short* __restrict__ Mpk, const unsigned short* __restrict__ Wpk,
    float* __restrict__ out, int V, int S)
{
    __shared__ unsigned sA[CAP][64];   // bf16-packed rows (26.6 KB)
    __shared__ float    sE[G][128];    // ebar, later etilde (2 KB)
    __shared__ float    sQ[G][128];    // q (2 KB)

    const int tid  = threadIdx.x;
    const int w    = tid >> 6;       // wave id = local segment id
    const int lane = tid & 63;
    const int s0   = blockIdx.x * G;

    const int se    = min(s0 + G, S);
    const int gr0   = starts[s0];
    const int nrows = starts[se] - gr0;
    const bool staged = (nrows <= CAP);

    const int c  = lane & 31;        // column quad (sweeps)
    const int g  = lane >> 5;        // row parity (sweeps)

    // ---------------- stage: E rows -> bf16 LDS (batches 5/5/3) ------------
    if (staged && nrows > 0) {
        const int q4 = tid & 31;
        const int rr = tid >> 5;                 // 0..7, stride 8
        const float* gp = E + (size_t)gr0 * 128 + q4 * 4;
#pragma unroll
        for (int b = 0; b < 3; ++b) {
            const int nb = (b == 2) ? 3 : 5;
            const int k0 = b * 5;
            float4 t[5];
            for (int k = 0; k < nb; ++k) {
                const int r = min(rr + (k0 + k) * 8, nrows - 1);   // clamp: dup
                t[k] = *(const float4*)(gp + (size_t)r * 128);
            }
            for (int k = 0; k < nb; ++k) {
                uint2 u;
                u.x = f2bf_rte(t[k].x) | (f2bf_rte(t[k].y) << 16);
                u.y = f2bf_rte(t[k].z) | (f2bf_rte(t[k].w) << 16);
                *(uint2*)&sA[rr + (k0 + k) * 8][q4 * 2] = u;       // dup unread
            }
        }
    }
    __syncthreads();                                            // B1

    // per-wave segment meta
    const int segi = s0 + w;
    int r0 = 0, n = 0, off = 0;
    if (segi < S) {
        r0  = starts[segi];
        n   = starts[segi + 1] - r0;
        off = r0 - gr0;
    }

    // ---------------- mean: ebar[w] ----------------------------------------
    {
        float4 sum = make_float4(0.f, 0.f, 0.f, 0.f);
        if (segi < S && n > 0) {
            if (staged) {
#pragma unroll 4
                for (int rp = 0; rp < n; rp += 2) {
                    const int row = rp + g;
                    const int rcl = min(row, n - 1);
                    const uint2 u = *(const uint2*)&sA[off + rcl][c * 2];
                    const float m = (row < n) ? 1.f : 0.f;
                    sum.x += m * bfu_lo(u.x); sum.y += m * bfu_hi(u.x);
                    sum.z += m * bfu_lo(u.y); sum.w += m * bfu_hi(u.y);
                }
            } else {
                const float* bp = E + (size_t)r0 * 128 + c * 4;
#pragma unroll 4
                for (int rp = 0; rp < n; rp += 2) {
                    const int row = rp + g;
                    const int rcl = min(row, n - 1);
                    const float4 ev = *(const float4*)(bp + (size_t)rcl * 128);
                    const float m = (row < n) ? 1.f : 0.f;
                    sum.x += m * ev.x; sum.y += m * ev.y;
                    sum.z += m * ev.z; sum.w += m * ev.w;
                }
            }
            sum.x += __shfl_xor(sum.x, 32);
            sum.y += __shfl_xor(sum.y, 32);
            sum.z += __shfl_xor(sum.z, 32);
            sum.w += __shfl_xor(sum.w, 32);
            const float inv = 1.0f / (float)n;
            sum.x *= inv; sum.y *= inv; sum.z *= inv; sum.w *= inv;
        }
        if (g == 0)
            *(float4*)&sE[w][c * 4] = sum;    // zeros when segi>=S or n==0
    }
    __syncthreads();                                            // B2

    // ---------------- q GEMM via MFMA: sQ = sE @ M -------------------------
    const int arow = lane & 15;       // A row / C col
    const int akg  = lane >> 4;       // k-group
    {
        f32x4 c0 = {0.f, 0.f, 0.f, 0.f};
        f32x4 c1 = {0.f, 0.f, 0.f, 0.f};
        const uint4* Bp = (const uint4*)Mpk;
#pragma unroll
        for (int kt = 0; kt < 4; ++kt) {
            const bf16x8 a = pack_a8(&sE[arow & 3][kt * 32 + akg * 8]);
            union { uint4 u; bf16x8 v; } b0, b1;
            b0.u = Bp[(size_t)(kt * 8 + 2 * w) * 64 + lane];
            b1.u = Bp[(size_t)(kt * 8 + 2 * w + 1) * 64 + lane];
            c0 = __builtin_amdgcn_mfma_f32_16x16x32_bf16(a, b0.v, c0, 0, 0, 0);
            c1 = __builtin_amdgcn_mfma_f32_16x16x32_bf16(a, b1.v, c1, 0, 0, 0);
        }
        if (akg == 0) {                       // C rows 0-3 live in lanes 0-15
#pragma unroll
            for (int r = 0; r < 4; ++r) {
                sQ[r][(2 * w) * 16 + arow]     = c0[r];
                sQ[r][(2 * w + 1) * 16 + arow] = c1[r];
            }
        }
    }
    __syncthreads();                                            // B3

    // ---------------- attn: merged scores + exp2 + weighted sum ------------
    {
        float4 acc = make_float4(0.f, 0.f, 0.f, 0.f);
        float Z = 0.f;
        if (segi < S && n > 0) {
            const float LOG2E = 1.4426950408889634f;
            float4 qv = *(const float4*)&sQ[w][c * 4];
            qv.x *= LOG2E; qv.y *= LOG2E; qv.z *= LOG2E; qv.w *= LOG2E;
            if (staged) {
#pragma unroll 4
                for (int rp = 0; rp < n; rp += 2) {
                    const int row = rp + g;
                    const int rcl = min(row, n - 1);
                    const uint2 u = *(const uint2*)&sA[off + rcl][c * 2];
                    const float e0 = bfu_lo(u.x), e1 = bfu_hi(u.x);
                    const float e2 = bfu_lo(u.y), e3 = bfu_hi(u.y);
                    float pd = e0 * qv.x + e1 * qv.y + e2 * qv.z + e3 * qv.w;
                    pd += __shfl_xor(pd, 1);
                    pd += __shfl_xor(pd, 2);
                    pd += __shfl_xor(pd, 4);
                    pd += __shfl_xor(pd, 8);
                    pd += __shfl_xor(pd, 16);
                    const float wgt = (row < n) ? exp2f(pd) : 0.f;
                    Z += wgt;
                    acc.x += wgt * e0; acc.y += wgt * e1;
                    acc.z += wgt * e2; acc.w += wgt * e3;
                }
            } else {
                const float* bp = E + (size_t)r0 * 128 + c * 4;
#pragma unroll 4
                for (int rp = 0; rp < n; rp += 2) {
                    const int row = rp + g;
                    const int rcl = min(row, n - 1);
                    const float4 ev = *(const float4*)(bp + (size_t)rcl * 128);
                    float pd = ev.x * qv.x + ev.y * qv.y
                             + ev.z * qv.z + ev.w * qv.w;
                    pd += __shfl_xor(pd, 1);
                    pd += __shfl_xor(pd, 2);
                    pd += __shfl_xor(pd, 4);
                    pd += __shfl_xor(pd, 8);
                    pd += __shfl_xor(pd, 16);
                    const float wgt = (row < n) ? exp2f(pd) : 0.f;
                    Z += wgt;
                    acc.x += wgt * ev.x; acc.y += wgt * ev.y;
                    acc.z += wgt * ev.z; acc.w += wgt * ev.w;
                }
            }
            acc.x += __shfl_xor(acc.x, 32);
            acc.y += __shfl_xor(acc.y, 32);
            acc.z += __shfl_xor(acc.z, 32);
            acc.w += __shfl_xor(acc.w, 32);
            Z     += __shfl_xor(Z, 32);
            const float invZ = 1.0f / Z;
            acc.x *= invZ; acc.y *= invZ; acc.z *= invZ; acc.w *= invZ;
        }
        if (g == 0)
            *(float4*)&sE[w][c * 4] = acc;    // etilde (zeros if empty)
    }
    __syncthreads();                                            // B4

    // ---------------- out GEMM via MFMA: out = sE @ Wt ---------------------
    {
        f32x4 c0 = {0.f, 0.f, 0.f, 0.f};
        f32x4 c1 = {0.f, 0.f, 0.f, 0.f};
        const uint4* Bp = (const uint4*)Wpk;
#pragma unroll
        for (int kt = 0; kt < 4; ++kt) {
            const bf16x8 a = pack_a8(&sE[arow & 3][kt * 32 + akg * 8]);
            union { uint4 u; bf16x8 v; } b0, b1;
            b0.u = Bp[(size_t)(kt * 8 + 2 * w) * 64 + lane];
            b1.u = Bp[(size_t)(kt * 8 + 2 * w + 1) * 64 + lane];
            c0 = __builtin_amdgcn_mfma_f32_16x16x32_bf16(a, b0.v, c0, 0, 0, 0);
            c1 = __builtin_amdgcn_mfma_f32_16x16x32_bf16(a, b1.v, c1, 0, 0, 0);
        }
        if (akg == 0) {
#pragma unroll
            for (int r = 0; r < 4; ++r) {
                const int s = s0 + r;
                if (s < S) {
                    out[(size_t)s * 128 + (2 * w) * 16 + arow]     = c0[r];
                    out[(size_t)s * 128 + (2 * w + 1) * 16 + arow] = c1[r];
                }
            }
        }
    }
}

// ---------------------------------------------------------------------------
extern "C" void kernel_launch(void* const* d_in, const int* in_sizes, int n_in,
                              void* d_out, int out_size, void* d_ws, size_t ws_size,
                              hipStream_t stream) {
    const float* E   = (const float*)d_in[0];
    const int*   map = (const int*)d_in[1];
    const float* Wk  = (const float*)d_in[3];
    const float* Wv  = (const float*)d_in[4];
    const float* Wo  = (const float*)d_in[5];
    float* out = (float*)d_out;

    const int V = in_sizes[1];
    const int S = out_size / 128;

    char* p = (char*)d_ws;
    auto alloc = [&](size_t b) {
        char* r = p;
        p += (b + 255) & ~(size_t)255;
        return r;
    };
    int*            starts = (int*)alloc((size_t)(S + 1) * sizeof(int));
    unsigned short* Mpk    = (unsigned short*)alloc(128 * 128 * sizeof(unsigned short));
    unsigned short* Wpk    = (unsigned short*)alloc(128 * 128 * sizeof(unsigned short));

    k_segstarts<<<(V + 255) / 256, 256, 0, stream>>>(map, starts, V, S);
    k_prep<<<128, 128, 0, stream>>>(Wk, Wv, Wo, Mpk, Wpk);
    k_main<<<(S + G - 1) / G, 256, 0, stream>>>(E, starts, Mpk, Wpk, out, V, S);
}

// Round 16
// 137.868 us; speedup vs baseline: 1.8878x; 1.0510x over previous
//
#include <hip/hip_runtime.h>
#include <math.h>

#define G    4      // segments per block
#define CAP  104    // max staged rows per group (~0.4% fallback)

typedef __attribute__((ext_vector_type(8))) short bf16x8;
typedef __attribute__((ext_vector_type(4))) float f32x4;

// ---------------------------------------------------------------------------
__global__ void k_segstarts(const int* __restrict__ map, int* __restrict__ starts,
                            int V, int S) {
    int i = blockIdx.x * blockDim.x + threadIdx.x;
    if (i >= V) return;
    int cur  = map[i];
    int prev = (i == 0) ? -1 : map[i - 1];
    for (int s = prev + 1; s <= cur; ++s) starts[s] = i;
    if (i == V - 1) {
        for (int s = cur + 1; s <= S; ++s) starts[s] = V;
    }
}

__device__ __forceinline__ unsigned f2bf_rte(float x) {          // RTNE -> top 16
    unsigned b = __float_as_uint(x);
    b += 0x7FFFu + ((b >> 16) & 1u);
    return b >> 16;
}
__device__ __forceinline__ float bfu_lo(unsigned u) {
    return __uint_as_float(u << 16);
}
__device__ __forceinline__ float bfu_hi(unsigned u) {
    return __uint_as_float(u & 0xFFFF0000u);
}

// sum-butterfly: DPP adds (VALU pipe) + one ds_swizzle for xor16.
// dpp_ctrl must be a compile-time constant -> template parameter.
template <int CTRL>
__device__ __forceinline__ float dpp_add(float v) {
    int t = __builtin_amdgcn_update_dpp(0, __float_as_int(v), CTRL, 0xF, 0xF, true);
    return v + __int_as_float(t);
}
__device__ __forceinline__ float red32_sum(float v) {
    v = dpp_add<0xB1>(v);    // quad_perm(1,0,3,2): xor 1
    v = dpp_add<0x4E>(v);    // quad_perm(2,3,0,1): xor 2
    v = dpp_add<0x141>(v);   // row_half_mirror: xor 4 (8-sum)
    v = dpp_add<0x140>(v);   // row_mirror: xor 8 (16-sum)
    v += __int_as_float(__builtin_amdgcn_ds_swizzle(__float_as_int(v), 0x401F)); // xor16
    return v;                // all 32 lanes of each half hold the half-sum
}

// ---------------------------------------------------------------------------
// k_prep: M = (Wk^T Wv) * LOG2E  (baked so attn uses exp2 directly),
// Wt = Wo^T; both stored in MFMA B-fragment order (bf16).
// Fragment model (16x16x32): B col = lane&15, k = (lane>>4)*8 + t.
// ushort index = ((f*64 + lane)*8 + t), f = kt*8 + jt.
// ---------------------------------------------------------------------------
__global__ void k_prep(const float* __restrict__ Wk, const float* __restrict__ Wv,
                       const float* __restrict__ Wo,
                       unsigned short* __restrict__ Mpk,
                       unsigned short* __restrict__ Wpk) {
    const int i = blockIdx.x;     // k dim 0..127
    const int j = threadIdx.x;    // col  0..127
    float acc = 0.f;
#pragma unroll 8
    for (int h = 0; h < 128; ++h)
        acc += Wk[h * 128 + i] * Wv[h * 128 + j];
    acc *= 1.4426950408889634f;   // LOG2E baked into M -> q pre-scaled for exp2

    const int kt  = i >> 5;
    const int kg  = (i >> 3) & 3;
    const int t   = i & 7;
    const int jt  = j >> 4;
    const int l16 = j & 15;
    const int lane = kg * 16 + l16;
    const size_t idx = ((size_t)(kt * 8 + jt) * 64 + lane) * 8 + t;
    Mpk[idx] = (unsigned short)f2bf_rte(acc);
    Wpk[idx] = (unsigned short)f2bf_rte(Wo[j * 128 + i]);
}

// pack 8 consecutive fp32 -> bf16x8 (truncation)
__device__ __forceinline__ bf16x8 pack_a8(const float* p) {
    union { unsigned u[4]; bf16x8 v; } r;
    const float4 f0 = *(const float4*)p;
    const float4 f1 = *(const float4*)(p + 4);
    r.u[0] = (__float_as_uint(f0.y) & 0xFFFF0000u) | (__float_as_uint(f0.x) >> 16);
    r.u[1] = (__float_as_uint(f0.w) & 0xFFFF0000u) | (__float_as_uint(f0.z) >> 16);
    r.u[2] = (__float_as_uint(f1.y) & 0xFFFF0000u) | (__float_as_uint(f1.x) >> 16);
    r.u[3] = (__float_as_uint(f1.w) & 0xFFFF0000u) | (__float_as_uint(f1.z) >> 16);
    return r.v;
}

// ---------------------------------------------------------------------------
// k_main: bf16 E staged once in LDS; MFMA GEMM phases; DPP-reduced sweeps.
// Phases: stage -> B1 -> mean -> B2 -> qGEMM(mfma) -> B3 -> attn -> B4
//         -> outGEMM(mfma) -> global.
// ---------------------------------------------------------------------------
__global__ __launch_bounds__(256, 4) void k_main(
    const float* __restrict__ E, const int* __restrict__ starts,
    const unsigned short* __restrict__ Mpk, const unsigned short* __restrict__ Wpk,
    float* __restrict__ out, int V, int S)
{
    __shared__ unsigned sA[CAP][64];   // bf16-packed rows (26.6 KB)
    __shared__ float    sE[G][128];    // ebar, later etilde (2 KB)
    __shared__ float    sQ[G][128];    // q (2 KB)

    const int tid  = threadIdx.x;
    const int w    = tid >> 6;       // wave id = local segment id
    const int lane = tid & 63;
    const int s0   = blockIdx.x * G;

    const int se    = min(s0 + G, S);
    const int gr0   = starts[s0];
    const int nrows = starts[se] - gr0;
    const bool staged = (nrows <= CAP);

    const int c  = lane & 31;        // column quad (sweeps)
    const int g  = lane >> 5;        // row parity (sweeps)

    // ---------------- stage: E rows -> bf16 LDS (batches 5/5/3) ------------
    if (staged && nrows > 0) {
        const int q4 = tid & 31;
        const int rr = tid >> 5;                 // 0..7, stride 8
        const float* gp = E + (size_t)gr0 * 128 + q4 * 4;
#pragma unroll
        for (int b = 0; b < 3; ++b) {
            const int nb = (b == 2) ? 3 : 5;
            const int k0 = b * 5;
            float4 t[5];
            for (int k = 0; k < nb; ++k) {
                const int r = min(rr + (k0 + k) * 8, nrows - 1);   // clamp: dup
                t[k] = *(const float4*)(gp + (size_t)r * 128);
            }
            for (int k = 0; k < nb; ++k) {
                uint2 u;
                u.x = f2bf_rte(t[k].x) | (f2bf_rte(t[k].y) << 16);
                u.y = f2bf_rte(t[k].z) | (f2bf_rte(t[k].w) << 16);
                *(uint2*)&sA[rr + (k0 + k) * 8][q4 * 2] = u;       // dup unread
            }
        }
    }
    __syncthreads();                                            // B1

    // per-wave segment meta
    const int segi = s0 + w;
    int r0 = 0, n = 0, off = 0;
    if (segi < S) {
        r0  = starts[segi];
        n   = starts[segi + 1] - r0;
        off = r0 - gr0;
    }
    const int nfull = n & ~1;

    // ---------------- mean: ebar[w] (tail-split, no per-iter masks) --------
    {
        float4 sum = make_float4(0.f, 0.f, 0.f, 0.f);
        if (segi < S && n > 0) {
            if (staged) {
                const unsigned* pA = &sA[off + g][c * 2];
                for (int rp = 0; rp < nfull; rp += 2) {
                    const uint2 u = *(const uint2*)pA;
                    pA += 128;                           // 2 rows * 64 uints
                    sum.x += bfu_lo(u.x); sum.y += bfu_hi(u.x);
                    sum.z += bfu_lo(u.y); sum.w += bfu_hi(u.y);
                }
                if ((n & 1) && g == 0) {
                    const uint2 u = *(const uint2*)&sA[off + n - 1][c * 2];
                    sum.x += bfu_lo(u.x); sum.y += bfu_hi(u.x);
                    sum.z += bfu_lo(u.y); sum.w += bfu_hi(u.y);
                }
            } else {
                const float* bp = E + (size_t)r0 * 128 + c * 4;
                for (int rp = 0; rp < nfull; rp += 2) {
                    const float4 ev = *(const float4*)(bp + (size_t)(rp + g) * 128);
                    sum.x += ev.x; sum.y += ev.y; sum.z += ev.z; sum.w += ev.w;
                }
                if ((n & 1) && g == 0) {
                    const float4 ev = *(const float4*)(bp + (size_t)(n - 1) * 128);
                    sum.x += ev.x; sum.y += ev.y; sum.z += ev.z; sum.w += ev.w;
                }
            }
            sum.x += __shfl_xor(sum.x, 32);
            sum.y += __shfl_xor(sum.y, 32);
            sum.z += __shfl_xor(sum.z, 32);
            sum.w += __shfl_xor(sum.w, 32);
            const float inv = 1.0f / (float)n;
            sum.x *= inv; sum.y *= inv; sum.z *= inv; sum.w *= inv;
        }
        if (g == 0)
            *(float4*)&sE[w][c * 4] = sum;    // zeros when segi>=S or n==0
    }
    __syncthreads();                                            // B2

    // ---------------- q GEMM via MFMA: sQ = sE @ M -------------------------
    const int arow = lane & 15;       // A row / C col
    const int akg  = lane >> 4;       // k-group
    {
        f32x4 c0 = {0.f, 0.f, 0.f, 0.f};
        f32x4 c1 = {0.f, 0.f, 0.f, 0.f};
        const uint4* Bp = (const uint4*)Mpk;
#pragma unroll
        for (int kt = 0; kt < 4; ++kt) {
            const bf16x8 a = pack_a8(&sE[arow & 3][kt * 32 + akg * 8]);
            union { uint4 u; bf16x8 v; } b0, b1;
            b0.u = Bp[(size_t)(kt * 8 + 2 * w) * 64 + lane];
            b1.u = Bp[(size_t)(kt * 8 + 2 * w + 1) * 64 + lane];
            c0 = __builtin_amdgcn_mfma_f32_16x16x32_bf16(a, b0.v, c0, 0, 0, 0);
            c1 = __builtin_amdgcn_mfma_f32_16x16x32_bf16(a, b1.v, c1, 0, 0, 0);
        }
        if (akg == 0) {                       // C rows 0-3 live in lanes 0-15
#pragma unroll
            for (int r = 0; r < 4; ++r) {
                sQ[r][(2 * w) * 16 + arow]     = c0[r];
                sQ[r][(2 * w + 1) * 16 + arow] = c1[r];
            }
        }
    }
    __syncthreads();                                            // B3

    // ---------------- attn: scores + exp2 + weighted sum (DPP reduce) ------
    {
        float4 acc = make_float4(0.f, 0.f, 0.f, 0.f);
        float Z = 0.f;
        if (segi < S && n > 0) {
            const float4 qv = *(const float4*)&sQ[w][c * 4];   // pre-scaled by LOG2E
            if (staged) {
                const unsigned* pA = &sA[off + g][c * 2];
                for (int rp = 0; rp < nfull; rp += 2) {
                    const uint2 u = *(const uint2*)pA;
                    pA += 128;
                    const float e0 = bfu_lo(u.x), e1 = bfu_hi(u.x);
                    const float e2 = bfu_lo(u.y), e3 = bfu_hi(u.y);
                    float pd = e0 * qv.x + e1 * qv.y + e2 * qv.z + e3 * qv.w;
                    pd = red32_sum(pd);
                    const float wgt = exp2f(pd);
                    Z += wgt;
                    acc.x += wgt * e0; acc.y += wgt * e1;
                    acc.z += wgt * e2; acc.w += wgt * e3;
                }
                if ((n & 1) && g == 0) {
                    const uint2 u = *(const uint2*)&sA[off + n - 1][c * 2];
                    const float e0 = bfu_lo(u.x), e1 = bfu_hi(u.x);
                    const float e2 = bfu_lo(u.y), e3 = bfu_hi(u.y);
                    float pd = e0 * qv.x + e1 * qv.y + e2 * qv.z + e3 * qv.w;
                    pd = red32_sum(pd);                 // lanes 0-31 all active
                    const float wgt = exp2f(pd);
                    Z += wgt;
                    acc.x += wgt * e0; acc.y += wgt * e1;
                    acc.z += wgt * e2; acc.w += wgt * e3;
                }
            } else {
                const float* bp = E + (size_t)r0 * 128 + c * 4;
                for (int rp = 0; rp < nfull; rp += 2) {
                    const float4 ev = *(const float4*)(bp + (size_t)(rp + g) * 128);
                    float pd = ev.x * qv.x + ev.y * qv.y
                             + ev.z * qv.z + ev.w * qv.w;
                    pd = red32_sum(pd);
                    const float wgt = exp2f(pd);
                    Z += wgt;
                    acc.x += wgt * ev.x; acc.y += wgt * ev.y;
                    acc.z += wgt * ev.z; acc.w += wgt * ev.w;
                }
                if ((n & 1) && g == 0) {
                    const float4 ev = *(const float4*)(bp + (size_t)(n - 1) * 128);
                    float pd = ev.x * qv.x + ev.y * qv.y
                             + ev.z * qv.z + ev.w * qv.w;
                    pd = red32_sum(pd);
                    const float wgt = exp2f(pd);
                    Z += wgt;
                    acc.x += wgt * ev.x; acc.y += wgt * ev.y;
                    acc.z += wgt * ev.z; acc.w += wgt * ev.w;
                }
            }
            acc.x += __shfl_xor(acc.x, 32);
            acc.y += __shfl_xor(acc.y, 32);
            acc.z += __shfl_xor(acc.z, 32);
            acc.w += __shfl_xor(acc.w, 32);
            Z     += __shfl_xor(Z, 32);
            const float invZ = 1.0f / Z;
            acc.x *= invZ; acc.y *= invZ; acc.z *= invZ; acc.w *= invZ;
        }
        if (g == 0)
            *(float4*)&sE[w][c * 4] = acc;    // etilde (zeros if empty)
    }
    __syncthreads();                                            // B4

    // ---------------- out GEMM via MFMA: out = sE @ Wt ---------------------
    {
        f32x4 c0 = {0.f, 0.f, 0.f, 0.f};
        f32x4 c1 = {0.f, 0.f, 0.f, 0.f};
        const uint4* Bp = (const uint4*)Wpk;
#pragma unroll
        for (int kt = 0; kt < 4; ++kt) {
            const bf16x8 a = pack_a8(&sE[arow & 3][kt * 32 + akg * 8]);
            union { uint4 u; bf16x8 v; } b0, b1;
            b0.u = Bp[(size_t)(kt * 8 + 2 * w) * 64 + lane];
            b1.u = Bp[(size_t)(kt * 8 + 2 * w + 1) * 64 + lane];
            c0 = __builtin_amdgcn_mfma_f32_16x16x32_bf16(a, b0.v, c0, 0, 0, 0);
            c1 = __builtin_amdgcn_mfma_f32_16x16x32_bf16(a, b1.v, c1, 0, 0, 0);
        }
        if (akg == 0) {
#pragma unroll
            for (int r = 0; r < 4; ++r) {
                const int s = s0 + r;
                if (s < S) {
                    out[(size_t)s * 128 + (2 * w) * 16 + arow]     = c0[r];
                    out[(size_t)s * 128 + (2 * w + 1) * 16 + arow] = c1[r];
                }
            }
        }
    }
}

// ---------------------------------------------------------------------------
extern "C" void kernel_launch(void* const* d_in, const int* in_sizes, int n_in,
                              void* d_out, int out_size, void* d_ws, size_t ws_size,
                              hipStream_t stream) {
    const float* E   = (const float*)d_in[0];
    const int*   map = (const int*)d_in[1];
    const float* Wk  = (const float*)d_in[3];
    const float* Wv  = (const float*)d_in[4];
    const float* Wo  = (const float*)d_in[5];
    float* out = (float*)d_out;

    const int V = in_sizes[1];
    const int S = out_size / 128;

    char* p = (char*)d_ws;
    auto alloc = [&](size_t b) {
        char* r = p;
        p += (b + 255) & ~(size_t)255;
        return r;
    };
    int*            starts = (int*)alloc((size_t)(S + 1) * sizeof(int));
    unsigned short* Mpk    = (unsigned short*)alloc(128 * 128 * sizeof(unsigned short));
    unsigned short* Wpk    = (unsigned short*)alloc(128 * 128 * sizeof(unsigned short));

    k_segstarts<<<(V + 255) / 256, 256, 0, stream>>>(map, starts, V, S);
    k_prep<<<128, 128, 0, stream>>>(Wk, Wv, Wo, Mpk, Wpk);
    k_main<<<(S + G - 1) / G, 256, 0, stream>>>(E, starts, Mpk, Wpk, out, V, S);
}